// Round 6
// baseline (1019.117 us; speedup 1.0000x reference)
//
#include <hip/hip_runtime.h>
#include <hip/hip_bf16.h>

// Problem constants
#define NH 4
#define DKV 64
#define DM 256
#define NB 8
#define NL 2048
#define LN_EPS 1e-5f

typedef __hip_bfloat16 bf16;
typedef __attribute__((ext_vector_type(8))) short short8;
typedef __attribute__((ext_vector_type(4))) short s16x4;  // NB: 'short4' is a HIP builtin
typedef __attribute__((ext_vector_type(4))) float f32x4;

#define MFMA(a, b, c) __builtin_amdgcn_mfma_f32_16x16x32_bf16((a), (b), (c), 0, 0, 0)

__device__ __forceinline__ short f2bf(float f) {
  __hip_bfloat16 h = __float2bfloat16(f);
  return *reinterpret_cast<short*>(&h);
}

// ---------------------------------------------------------------------------
// Kernel 1: transpose weights to [N][K] bf16, precompute additive mask.
// ---------------------------------------------------------------------------
__global__ __launch_bounds__(256) void prep_kernel(
    const float* __restrict__ wq, const float* __restrict__ wk,
    const float* __restrict__ wv, const float* __restrict__ wf,
    const int* __restrict__ mask, bf16* __restrict__ wqT,
    bf16* __restrict__ wkT, bf16* __restrict__ wvT, bf16* __restrict__ wfT,
    float* __restrict__ maskadd) {
  int idx = blockIdx.x * 256 + threadIdx.x;
  if (idx < 4 * 65536) {
    int w = idx >> 16;
    int rem = idx & 65535;
    int k = rem >> 8, n = rem & 255;
    const float* src = (w == 0) ? wq : (w == 1) ? wk : (w == 2) ? wv : wf;
    bf16* dst = (w == 0) ? wqT : (w == 1) ? wkT : (w == 2) ? wvT : wfT;
    dst[n * 256 + k] = __float2bfloat16(src[k * 256 + n]);
  } else {
    int i = idx - 4 * 65536;
    if (i < NB * NL) maskadd[i] = mask[i] ? -1e30f : 0.0f;
  }
}

// ---------------------------------------------------------------------------
// Kernel 2: projection GEMM  Y = X @ W^T(bf16) + bias.
// MODE 0: Y row-major bf16 (qh/kh), scale folds 1/sqrt(dk) for qh.
//         C-layout: n(lane&15)=out col, m(g*4+r)=out row.
// MODE 1: swapped operands -> C^T in regs: n(lane&15)=out ROW (kpos),
//         m(g*4+r)=out COL (dv). Store vhT[b][h][dv][kpos] with lanes
//         contiguous along kpos (32B segments instead of 2B x 4KB scatter).
// ---------------------------------------------------------------------------
template <int MODE>
__global__ __launch_bounds__(256) void proj_kernel(
    const float* __restrict__ x, const bf16* __restrict__ wT,
    const float* __restrict__ bias, float scale, bf16* __restrict__ out) {
  int lane = threadIdx.x & 63;
  int w = threadIdx.x >> 6;
  int col = lane & 15, g = lane >> 4;
  int rbase = blockIdx.x * 64 + w * 16;
  int cbase = blockIdx.y * 64;

  f32x4 acc[4] = {{0.f, 0.f, 0.f, 0.f},
                  {0.f, 0.f, 0.f, 0.f},
                  {0.f, 0.f, 0.f, 0.f},
                  {0.f, 0.f, 0.f, 0.f}};
  const float* ap = x + (size_t)(rbase + col) * DM;

#pragma unroll
  for (int ks = 0; ks < 8; ++ks) {
    int koff = ks * 32 + g * 8;
    f32x4 x0 = *(const f32x4*)(ap + koff);
    f32x4 x1 = *(const f32x4*)(ap + koff + 4);
    short8 a;
    a[0] = f2bf(x0[0]); a[1] = f2bf(x0[1]); a[2] = f2bf(x0[2]); a[3] = f2bf(x0[3]);
    a[4] = f2bf(x1[0]); a[5] = f2bf(x1[1]); a[6] = f2bf(x1[2]); a[7] = f2bf(x1[3]);
#pragma unroll
    for (int ct = 0; ct < 4; ++ct) {
      short8 b = *(const short8*)(wT + (size_t)(cbase + ct * 16 + col) * DM + koff);
      if (MODE == 0)
        acc[ct] = MFMA(a, b, acc[ct]);
      else
        acc[ct] = MFMA(b, a, acc[ct]);  // C^T: rows<->cols
    }
  }

  if (MODE == 0) {
#pragma unroll
    for (int ct = 0; ct < 4; ++ct) {
      int cg = cbase + ct * 16 + col;
      float bv = bias[cg];
#pragma unroll
      for (int r = 0; r < 4; ++r) {
        int rg = rbase + g * 4 + r;
        out[(size_t)rg * DM + cg] = __float2bfloat16((acc[ct][r] + bv) * scale);
      }
    }
  } else {
    int rg = rbase + col;                 // Y row = kpos index
    int bI = rg >> 11, kpos = rg & (NL - 1);
    int hh = cbase >> 6;                  // 64-aligned head block
    bf16* obase = out + ((size_t)(bI * NH + hh) * 64) * NL + kpos;
#pragma unroll
    for (int ct = 0; ct < 4; ++ct) {
      f32x4 bv = *(const f32x4*)(bias + cbase + ct * 16 + g * 4);
#pragma unroll
      for (int r = 0; r < 4; ++r) {
        int dv = ct * 16 + g * 4 + r;     // Y col (dv) local to head
        obase[(size_t)dv * NL] = __float2bfloat16(acc[ct][r] + bv[r]);
      }
    }
  }
}

// ---------------------------------------------------------------------------
// Kernel 3: attention, swapped-operand S^T scheme.
// Per lane: q = qbase + col (fixed), k = kt + ct*16 + g*4 + r.
// Pass A: l = sum_k exp(s+mask) (no max; scores are O(0.1)), per-lane
//         accumulate, one xor-16/32 reduce at the end.
// Pass B: p = exp(s+mask)*inv_l -> dwordx4 store (4 consecutive k) +
//         packed b64 LDS write -> per-wave transpose -> PV MFMA.
// ---------------------------------------------------------------------------
__global__ __launch_bounds__(256) void attn_kernel(
    const bf16* __restrict__ qh, const bf16* __restrict__ kh,
    const bf16* __restrict__ vhT, const float* __restrict__ maskadd,
    float* __restrict__ attn_f, float* __restrict__ aout) {
  __shared__ bf16 ldsP[4][16][72];  // [wave][q 16][k 64, padded]

  int lane = threadIdx.x & 63;
  int w = threadIdx.x >> 6;
  int col = lane & 15, g = lane >> 4;

  int bid = blockIdx.x;
  int qt = bid & 31;
  int bh = bid >> 5;  // h*8 + b == attn row-block index
  int b = bh & 7, h = bh >> 3;
  int qbase = qt * 64 + w * 16;

  const bf16* qrow = qh + (size_t)(b * NL + qbase + col) * DM + h * 64;
  short8 aq0 = *(const short8*)(qrow + g * 8);
  short8 aq1 = *(const short8*)(qrow + 32 + g * 8);

  const bf16* khb = kh + (size_t)(b * NL) * DM + h * 64;
  const bf16* vtb = vhT + (size_t)((b * NH + h) * 64) * NL;
  const float* madd_b = maskadd + b * NL;

  // ---- Pass A: denominator only ----
  float l = 0.f;
  for (int kt = 0; kt < NL; kt += 64) {
#pragma unroll
    for (int ct = 0; ct < 4; ++ct) {
      int krow = kt + ct * 16 + col;  // A-fragment row via lane col
      const bf16* kpr = khb + (size_t)krow * DM;
      short8 b0 = *(const short8*)(kpr + g * 8);
      short8 b1 = *(const short8*)(kpr + 32 + g * 8);
      f32x4 c = {0.f, 0.f, 0.f, 0.f};
      c = MFMA(b0, aq0, c);  // S^T: m=k_local, n=q
      c = MFMA(b1, aq1, c);
      f32x4 ma = *(const f32x4*)(madd_b + kt + ct * 16 + g * 4);
      l += __expf(c[0] + ma[0]) + __expf(c[1] + ma[1]) +
           __expf(c[2] + ma[2]) + __expf(c[3] + ma[3]);
    }
  }
  l += __shfl_xor(l, 16);
  l += __shfl_xor(l, 32);
  float inv_l = 1.0f / l;  // per lane's q-row (q = qbase+col)

  // ---- Pass B: normalized P out + PV ----
  f32x4 accO[4] = {{0.f, 0.f, 0.f, 0.f},
                   {0.f, 0.f, 0.f, 0.f},
                   {0.f, 0.f, 0.f, 0.f},
                   {0.f, 0.f, 0.f, 0.f}};
  float* attn_base = attn_f + (size_t)bh * NL * NL + (size_t)(qbase + col) * NL;

  for (int kt = 0; kt < NL; kt += 64) {
#pragma unroll
    for (int ct = 0; ct < 4; ++ct) {
      int krow = kt + ct * 16 + col;
      const bf16* kpr = khb + (size_t)krow * DM;
      short8 b0 = *(const short8*)(kpr + g * 8);
      short8 b1 = *(const short8*)(kpr + 32 + g * 8);
      f32x4 c = {0.f, 0.f, 0.f, 0.f};
      c = MFMA(b0, aq0, c);
      c = MFMA(b1, aq1, c);
      f32x4 ma = *(const f32x4*)(madd_b + kt + ct * 16 + g * 4);
      f32x4 p;
      p[0] = __expf(c[0] + ma[0]) * inv_l;
      p[1] = __expf(c[1] + ma[1]) * inv_l;
      p[2] = __expf(c[2] + ma[2]) * inv_l;
      p[3] = __expf(c[3] + ma[3]) * inv_l;
      *(f32x4*)(attn_base + kt + ct * 16 + g * 4) = p;  // 4 consecutive k
      s16x4 pk;
      pk[0] = f2bf(p[0]); pk[1] = f2bf(p[1]);
      pk[2] = f2bf(p[2]); pk[3] = f2bf(p[3]);
      *(s16x4*)(&ldsP[w][col][ct * 16 + g * 4]) = pk;  // one b64 write
    }
    // per-wave transpose read: A-fragment P[q=col][k] (lgkmcnt by compiler)
    short8 ap0 = *(const short8*)(&ldsP[w][col][g * 8]);
    short8 ap1 = *(const short8*)(&ldsP[w][col][32 + g * 8]);
#pragma unroll
    for (int dvt = 0; dvt < 4; ++dvt) {
      const bf16* vp = vtb + (size_t)(dvt * 16 + col) * NL + kt;
      short8 v0 = *(const short8*)(vp + g * 8);
      short8 v1 = *(const short8*)(vp + 32 + g * 8);
      accO[dvt] = MFMA(ap0, v0, accO[dvt]);
      accO[dvt] = MFMA(ap1, v1, accO[dvt]);
    }
  }

#pragma unroll
  for (int dvt = 0; dvt < 4; ++dvt)
#pragma unroll
    for (int r = 0; r < 4; ++r)
      aout[(size_t)(b * NL + qbase + g * 4 + r) * DM + h * 64 + dvt * 16 + col] =
          accO[dvt][r];
}

// ---------------------------------------------------------------------------
// Kernel 4: out = LN(aout @ wf + bf + residual). Col-split: block = 16 rows,
// 4 waves each own a 64-col slice; LN sums combined via LDS. Grid 1024.
// ---------------------------------------------------------------------------
__global__ __launch_bounds__(256) void final_kernel(
    const float* __restrict__ aout, const bf16* __restrict__ wfT,
    const float* __restrict__ bf_, const float* __restrict__ resid,
    const float* __restrict__ gamma, const float* __restrict__ beta,
    float* __restrict__ out) {
  __shared__ float lsum[16][4];
  __shared__ float lsq[16][4];
  int lane = threadIdx.x & 63;
  int w = threadIdx.x >> 6;  // wave's col slice: [w*64, w*64+64)
  int col = lane & 15, g = lane >> 4;
  int rbase = blockIdx.x * 16;

  f32x4 acc[4];
#pragma unroll
  for (int ct = 0; ct < 4; ++ct) acc[ct] = (f32x4){0.f, 0.f, 0.f, 0.f};

  const float* ap = aout + (size_t)(rbase + col) * DM;
#pragma unroll
  for (int ks = 0; ks < 8; ++ks) {
    int koff = ks * 32 + g * 8;
    f32x4 x0 = *(const f32x4*)(ap + koff);
    f32x4 x1 = *(const f32x4*)(ap + koff + 4);
    short8 a;
    a[0] = f2bf(x0[0]); a[1] = f2bf(x0[1]); a[2] = f2bf(x0[2]); a[3] = f2bf(x0[3]);
    a[4] = f2bf(x1[0]); a[5] = f2bf(x1[1]); a[6] = f2bf(x1[2]); a[7] = f2bf(x1[3]);
#pragma unroll
    for (int ct = 0; ct < 4; ++ct) {
      short8 b = *(const short8*)(wfT + (size_t)(w * 64 + ct * 16 + col) * DM + koff);
      acc[ct] = MFMA(a, b, acc[ct]);
    }
  }

  float sum[4] = {0.f, 0.f, 0.f, 0.f}, sq[4] = {0.f, 0.f, 0.f, 0.f};
#pragma unroll
  for (int ct = 0; ct < 4; ++ct) {
    int cg = w * 64 + ct * 16 + col;
    float bv = bf_[cg];
#pragma unroll
    for (int r = 0; r < 4; ++r) {
      int rg = rbase + g * 4 + r;
      float xv = acc[ct][r] + bv + resid[(size_t)rg * DM + cg];
      acc[ct][r] = xv;
      sum[r] += xv;
      sq[r] += xv * xv;
    }
  }
#pragma unroll
  for (int st = 1; st <= 8; st <<= 1)
#pragma unroll
    for (int r = 0; r < 4; ++r) {
      sum[r] += __shfl_xor(sum[r], st);
      sq[r] += __shfl_xor(sq[r], st);
    }
  if (col == 0) {
#pragma unroll
    for (int r = 0; r < 4; ++r) {
      lsum[g * 4 + r][w] = sum[r];
      lsq[g * 4 + r][w] = sq[r];
    }
  }
  __syncthreads();
  float mu[4], rstd[4];
#pragma unroll
  for (int r = 0; r < 4; ++r) {
    int row = g * 4 + r;
    float s_ = lsum[row][0] + lsum[row][1] + lsum[row][2] + lsum[row][3];
    float q_ = lsq[row][0] + lsq[row][1] + lsq[row][2] + lsq[row][3];
    mu[r] = s_ * (1.0f / 256.0f);
    float var = q_ * (1.0f / 256.0f) - mu[r] * mu[r];
    rstd[r] = rsqrtf(var + LN_EPS);
  }
#pragma unroll
  for (int ct = 0; ct < 4; ++ct) {
    int cg = w * 64 + ct * 16 + col;
    float gm = gamma[cg], bt = beta[cg];
#pragma unroll
    for (int r = 0; r < 4; ++r) {
      int rg = rbase + g * 4 + r;
      out[(size_t)rg * DM + cg] = gm * (acc[ct][r] - mu[r]) * rstd[r] + bt;
    }
  }
}

// ---------------------------------------------------------------------------
extern "C" void kernel_launch(void* const* d_in, const int* in_sizes, int n_in,
                              void* d_out, int out_size, void* d_ws,
                              size_t ws_size, hipStream_t stream) {
  const float* q     = (const float*)d_in[0];
  const float* k     = (const float*)d_in[1];
  const float* v     = (const float*)d_in[2];
  const int*   mask  = (const int*)d_in[3];
  const float* wq    = (const float*)d_in[4];
  const float* bq    = (const float*)d_in[5];
  const float* wk    = (const float*)d_in[6];
  const float* bk    = (const float*)d_in[7];
  const float* wv    = (const float*)d_in[8];
  const float* bv    = (const float*)d_in[9];
  const float* wf    = (const float*)d_in[10];
  const float* bf_   = (const float*)d_in[11];
  const float* gamma = (const float*)d_in[12];
  const float* beta  = (const float*)d_in[13];

  char* ws = (char*)d_ws;
  bf16* wqT = (bf16*)(ws);
  bf16* wkT = (bf16*)(ws + (1 << 17));
  bf16* wvT = (bf16*)(ws + 2 * (1 << 17));
  bf16* wfT = (bf16*)(ws + 3 * (1 << 17));
  float* maskadd = (float*)(ws + 4 * (1 << 17));
  bf16* qh = (bf16*)(ws + 4 * (1 << 17) + (1 << 16));
  bf16* kh = qh + (size_t)16384 * 256;
  bf16* vhT = kh + (size_t)16384 * 256;
  float* aout = (float*)(vhT + (size_t)16384 * 256);

  float* out_f = (float*)d_out;
  float* attn_f = out_f + (size_t)16384 * 256;

  prep_kernel<<<1088, 256, 0, stream>>>(wq, wk, wv, wf, mask, wqT, wkT, wvT,
                                        wfT, maskadd);
  proj_kernel<0><<<dim3(256, 4), 256, 0, stream>>>(q, wqT, bq, 0.125f, qh);
  proj_kernel<0><<<dim3(256, 4), 256, 0, stream>>>(k, wkT, bk, 1.0f, kh);
  proj_kernel<1><<<dim3(256, 4), 256, 0, stream>>>(v, wvT, bv, 1.0f, vhT);
  attn_kernel<<<1024, 256, 0, stream>>>(qh, kh, vhT, maskadd, attn_f, aout);
  final_kernel<<<1024, 256, 0, stream>>>(aout, wfT, bf_, q, gamma, beta, out_f);
}

// Round 7
// 783.085 us; speedup vs baseline: 1.3014x; 1.3014x over previous
//
#include <hip/hip_runtime.h>
#include <hip/hip_bf16.h>

// Problem constants
#define NH 4
#define DM 256
#define NB 8
#define NL 2048
#define LN_EPS 1e-5f

typedef __hip_bfloat16 bf16;
typedef __attribute__((ext_vector_type(8))) short short8;
typedef __attribute__((ext_vector_type(4))) short s16x4;  // 'short4' is a HIP builtin
typedef __attribute__((ext_vector_type(4))) float f32x4;

#define MFMA(a, b, c) __builtin_amdgcn_mfma_f32_16x16x32_bf16((a), (b), (c), 0, 0, 0)

__device__ __forceinline__ short f2bf(float f) {
  __hip_bfloat16 h = __float2bfloat16(f);
  return *reinterpret_cast<short*>(&h);
}

// async global->LDS, 16B per lane; LDS dest = wave-uniform base + lane*16
__device__ __forceinline__ void gload16(const void* g, void* l) {
  __builtin_amdgcn_global_load_lds(
      (const __attribute__((address_space(1))) void*)g,
      (__attribute__((address_space(3))) void*)l, 16, 0, 0);
}

// swizzled LDS byte offset for [64][64]bf16 tile (128B rows): row r, 16B chunk cc
// involution: byte b of row r lives at b ^ ((r&7)<<4)
__device__ __forceinline__ int swz(int r, int cc) {
  return r * 128 + (((cc) ^ (r & 7)) << 4);
}

// ---------------------------------------------------------------------------
// Kernel 1: transpose weights to [N][K] bf16, precompute additive mask.
// ---------------------------------------------------------------------------
__global__ __launch_bounds__(256) void prep_kernel(
    const float* __restrict__ wq, const float* __restrict__ wk,
    const float* __restrict__ wv, const float* __restrict__ wf,
    const int* __restrict__ mask, bf16* __restrict__ wqT,
    bf16* __restrict__ wkT, bf16* __restrict__ wvT, bf16* __restrict__ wfT,
    float* __restrict__ maskadd) {
  int idx = blockIdx.x * 256 + threadIdx.x;
  if (idx < 4 * 65536) {
    int w = idx >> 16;
    int rem = idx & 65535;
    int k = rem >> 8, n = rem & 255;
    const float* src = (w == 0) ? wq : (w == 1) ? wk : (w == 2) ? wv : wf;
    bf16* dst = (w == 0) ? wqT : (w == 1) ? wkT : (w == 2) ? wvT : wfT;
    dst[n * 256 + k] = __float2bfloat16(src[k * 256 + n]);
  } else {
    int i = idx - 4 * 65536;
    if (i < NB * NL) maskadd[i] = mask[i] ? -1e30f : 0.0f;
  }
}

// ---------------------------------------------------------------------------
// Kernel 2: projection GEMM  Y = X @ W^T(bf16) + bias. Both modes use
// swapped operands MFMA(b,a) => lane owns row (rbase+col), 4 consecutive
// cols per (ct): packed 8B stores.
// MODE 0: Y row-major bf16 [token][256] (qh/kh); scale folds 1/sqrt(dk).
// MODE 1: vhT[b][h][dv][kpos] (lane contiguous along kpos rows).
// ---------------------------------------------------------------------------
template <int MODE>
__global__ __launch_bounds__(256, 4) void proj_kernel(
    const float* __restrict__ x, const bf16* __restrict__ wT,
    const float* __restrict__ bias, float scale, bf16* __restrict__ out) {
  int lane = threadIdx.x & 63;
  int w = threadIdx.x >> 6;
  int col = lane & 15, g = lane >> 4;
  int rbase = blockIdx.x * 64 + w * 16;
  int cbase = blockIdx.y * 64;

  f32x4 acc[4] = {{0.f, 0.f, 0.f, 0.f},
                  {0.f, 0.f, 0.f, 0.f},
                  {0.f, 0.f, 0.f, 0.f},
                  {0.f, 0.f, 0.f, 0.f}};
  const float* ap = x + (size_t)(rbase + col) * DM;

#pragma unroll
  for (int ks = 0; ks < 8; ++ks) {
    int koff = ks * 32 + g * 8;
    f32x4 x0 = *(const f32x4*)(ap + koff);
    f32x4 x1 = *(const f32x4*)(ap + koff + 4);
    short8 a;
    a[0] = f2bf(x0[0]); a[1] = f2bf(x0[1]); a[2] = f2bf(x0[2]); a[3] = f2bf(x0[3]);
    a[4] = f2bf(x1[0]); a[5] = f2bf(x1[1]); a[6] = f2bf(x1[2]); a[7] = f2bf(x1[3]);
#pragma unroll
    for (int ct = 0; ct < 4; ++ct) {
      short8 b = *(const short8*)(wT + (size_t)(cbase + ct * 16 + col) * DM + koff);
      acc[ct] = MFMA(b, a, acc[ct]);  // C^T: lane -> row rbase+col, cols g*4+r
    }
  }

  int row = rbase + col;
  if (MODE == 0) {
    bf16* ob = out + (size_t)row * DM + cbase;
#pragma unroll
    for (int ct = 0; ct < 4; ++ct) {
      f32x4 bv = *(const f32x4*)(bias + cbase + ct * 16 + g * 4);
      s16x4 pk;
#pragma unroll
      for (int r = 0; r < 4; ++r) pk[r] = f2bf((acc[ct][r] + bv[r]) * scale);
      *(s16x4*)(ob + ct * 16 + g * 4) = pk;  // 8B store, 4 consecutive cols
    }
  } else {
    int bI = row >> 11, kpos = row & (NL - 1);
    int hh = cbase >> 6;
    bf16* obase = out + ((size_t)(bI * NH + hh) * 64) * NL + kpos;
#pragma unroll
    for (int ct = 0; ct < 4; ++ct) {
      f32x4 bv = *(const f32x4*)(bias + cbase + ct * 16 + g * 4);
#pragma unroll
      for (int r = 0; r < 4; ++r) {
        int dv = ct * 16 + g * 4 + r;
        obase[(size_t)dv * NL] = __float2bfloat16(acc[ct][r] + bv[r]);
      }
    }
  }
}

// ---------------------------------------------------------------------------
// Kernel 3: attention. Block = (b,h,64 q-rows), 4 waves. K/V tiles staged in
// LDS once per block (global_load_lds w16, XOR-swizzled via pre-swizzled
// global source), double-buffered 2-phase. Swapped-operand S^T as Round 6.
// LDS: kbuf 2x8KB + vbuf 2x8KB + P 4x2KB = 40KB -> 4 blocks/CU.
// ---------------------------------------------------------------------------
__global__ __launch_bounds__(256, 4) void attn_kernel(
    const bf16* __restrict__ qh, const bf16* __restrict__ kh,
    const bf16* __restrict__ vhT, const float* __restrict__ maskadd,
    float* __restrict__ attn_f, float* __restrict__ aout) {
  __shared__ char lds[40960];

  int lane = threadIdx.x & 63;
  int w = threadIdx.x >> 6;
  int col = lane & 15, g = lane >> 4;
  char* pb = lds + 32768 + w * 2048;  // per-wave swizzled P tile [16][64]

  int bid = blockIdx.x;
  int qt = bid & 31;
  int bh = bid >> 5;  // h*8 + b
  int b = bh & 7, h = bh >> 3;
  int qbase = qt * 64 + w * 16;

  const bf16* qrow = qh + (size_t)(b * NL + qbase + col) * DM + h * 64;
  short8 aq0 = *(const short8*)(qrow + g * 8);
  short8 aq1 = *(const short8*)(qrow + 32 + g * 8);

  const bf16* khb = kh + (size_t)(b * NL) * DM + h * 64;
  const bf16* vtb = vhT + (size_t)((b * NH + h) * 64) * NL;
  const float* madd_b = maskadd + b * NL;

  // staging lane constants: lane covers tile row (rr*32 + w*8 + srow),
  // swizzled 16B chunk ((lane&7)^srow) -> inverse-swizzled global column.
  int srow = lane >> 3;                  // == row&7 for this lane
  int scol = ((lane & 7) ^ srow) * 8;    // elems
  int ldsw = w * 1024;                   // per-wave LDS byte base per round

  char* kcur = lds;          // kbuf0
  char* knxt = lds + 8192;   // kbuf1
  char* vcur = lds + 16384;  // vbuf0
  char* vnxt = lds + 24576;  // vbuf1

  // ---- Pass A: denominator only ----
#pragma unroll
  for (int rr = 0; rr < 2; ++rr)
    gload16(khb + (size_t)(rr * 32 + w * 8 + srow) * DM + scol,
            kcur + rr * 4096 + ldsw);
  __syncthreads();

  float l = 0.f;
  for (int kt = 0; kt < NL; kt += 64) {
    if (kt + 64 < NL) {
#pragma unroll
      for (int rr = 0; rr < 2; ++rr)
        gload16(khb + (size_t)(kt + 64 + rr * 32 + w * 8 + srow) * DM + scol,
                knxt + rr * 4096 + ldsw);
    }
#pragma unroll
    for (int ct = 0; ct < 4; ++ct) {
      int r = ct * 16 + col;
      short8 b0 = *(const short8*)(kcur + swz(r, g));
      short8 b1 = *(const short8*)(kcur + swz(r, g + 4));
      f32x4 c = {0.f, 0.f, 0.f, 0.f};
      c = MFMA(b0, aq0, c);  // S^T: m=k_local, n=q
      c = MFMA(b1, aq1, c);
      f32x4 ma = *(const f32x4*)(madd_b + kt + ct * 16 + g * 4);
      l += __expf(c[0] + ma[0]) + __expf(c[1] + ma[1]) +
           __expf(c[2] + ma[2]) + __expf(c[3] + ma[3]);
    }
    __syncthreads();  // drains vmcnt (compiler) -> next stage complete
    char* t = kcur; kcur = knxt; knxt = t;
  }
  l += __shfl_xor(l, 16);
  l += __shfl_xor(l, 32);
  float inv_l = 1.0f / l;  // lane's q-row (q = qbase+col)

  // ---- Pass B: normalized P out + PV ----
  f32x4 accO[4] = {{0.f, 0.f, 0.f, 0.f},
                   {0.f, 0.f, 0.f, 0.f},
                   {0.f, 0.f, 0.f, 0.f},
                   {0.f, 0.f, 0.f, 0.f}};
  float* attn_base = attn_f + (size_t)bh * NL * NL + (size_t)(qbase + col) * NL;

#pragma unroll
  for (int rr = 0; rr < 2; ++rr) {
    gload16(khb + (size_t)(rr * 32 + w * 8 + srow) * DM + scol,
            kcur + rr * 4096 + ldsw);
    gload16(vtb + (size_t)(rr * 32 + w * 8 + srow) * NL + scol,
            vcur + rr * 4096 + ldsw);
  }
  __syncthreads();

  for (int kt = 0; kt < NL; kt += 64) {
    if (kt + 64 < NL) {
#pragma unroll
      for (int rr = 0; rr < 2; ++rr) {
        gload16(khb + (size_t)(kt + 64 + rr * 32 + w * 8 + srow) * DM + scol,
                knxt + rr * 4096 + ldsw);
        gload16(vtb + (size_t)(rr * 32 + w * 8 + srow) * NL + (kt + 64) + scol,
                vnxt + rr * 4096 + ldsw);
      }
    }
#pragma unroll
    for (int ct = 0; ct < 4; ++ct) {
      int r = ct * 16 + col;
      short8 b0 = *(const short8*)(kcur + swz(r, g));
      short8 b1 = *(const short8*)(kcur + swz(r, g + 4));
      f32x4 c = {0.f, 0.f, 0.f, 0.f};
      c = MFMA(b0, aq0, c);
      c = MFMA(b1, aq1, c);
      f32x4 ma = *(const f32x4*)(madd_b + kt + ct * 16 + g * 4);
      f32x4 p;
      p[0] = __expf(c[0] + ma[0]) * inv_l;
      p[1] = __expf(c[1] + ma[1]) * inv_l;
      p[2] = __expf(c[2] + ma[2]) * inv_l;
      p[3] = __expf(c[3] + ma[3]) * inv_l;
      *(f32x4*)(attn_base + kt + ct * 16 + g * 4) = p;  // coalesced dwordx4
      s16x4 pk;
      pk[0] = f2bf(p[0]); pk[1] = f2bf(p[1]);
      pk[2] = f2bf(p[2]); pk[3] = f2bf(p[3]);
      // swizzled P write: row=col, elem-bytes ct*32+g*8 (XOR bits 4-6 only)
      *(s16x4*)(pb + col * 128 + ((ct * 32 + g * 8) ^ ((col & 7) << 4))) = pk;
    }
    // per-wave transpose read: P[q=col][k] A-fragments (lgkmcnt by compiler)
    short8 ap0 = *(const short8*)(pb + swz(col, g));
    short8 ap1 = *(const short8*)(pb + swz(col, g + 4));
#pragma unroll
    for (int dvt = 0; dvt < 4; ++dvt) {
      int r = dvt * 16 + col;
      short8 v0 = *(const short8*)(vcur + swz(r, g));
      short8 v1 = *(const short8*)(vcur + swz(r, g + 4));
      accO[dvt] = MFMA(ap0, v0, accO[dvt]);
      accO[dvt] = MFMA(ap1, v1, accO[dvt]);
    }
    __syncthreads();
    char* t = kcur; kcur = knxt; knxt = t;
    t = vcur; vcur = vnxt; vnxt = t;
  }

#pragma unroll
  for (int dvt = 0; dvt < 4; ++dvt)
#pragma unroll
    for (int r = 0; r < 4; ++r)
      aout[(size_t)(b * NL + qbase + g * 4 + r) * DM + h * 64 + dvt * 16 + col] =
          accO[dvt][r];
}

// ---------------------------------------------------------------------------
// Kernel 4: out = LN(aout @ wf + bf + residual). Swapped operands: lane owns
// row rbase+col, 16 cols (4 ct x 4). Row-reduce = 2 shuffles + LDS cross-wave.
// ---------------------------------------------------------------------------
__global__ __launch_bounds__(256, 4) void final_kernel(
    const float* __restrict__ aout, const bf16* __restrict__ wfT,
    const float* __restrict__ bf_, const float* __restrict__ resid,
    const float* __restrict__ gamma, const float* __restrict__ beta,
    float* __restrict__ out) {
  __shared__ float lsum[16][4];
  __shared__ float lsq[16][4];
  int lane = threadIdx.x & 63;
  int w = threadIdx.x >> 6;  // wave's col slice [w*64, w*64+64)
  int col = lane & 15, g = lane >> 4;
  int rbase = blockIdx.x * 16;

  f32x4 acc[4];
#pragma unroll
  for (int ct = 0; ct < 4; ++ct) acc[ct] = (f32x4){0.f, 0.f, 0.f, 0.f};

  const float* ap = aout + (size_t)(rbase + col) * DM;
#pragma unroll
  for (int ks = 0; ks < 8; ++ks) {
    int koff = ks * 32 + g * 8;
    f32x4 x0 = *(const f32x4*)(ap + koff);
    f32x4 x1 = *(const f32x4*)(ap + koff + 4);
    short8 a;
    a[0] = f2bf(x0[0]); a[1] = f2bf(x0[1]); a[2] = f2bf(x0[2]); a[3] = f2bf(x0[3]);
    a[4] = f2bf(x1[0]); a[5] = f2bf(x1[1]); a[6] = f2bf(x1[2]); a[7] = f2bf(x1[3]);
#pragma unroll
    for (int ct = 0; ct < 4; ++ct) {
      short8 b = *(const short8*)(wfT + (size_t)(w * 64 + ct * 16 + col) * DM + koff);
      acc[ct] = MFMA(b, a, acc[ct]);  // C^T: lane row=rbase+col, cols g*4+r
    }
  }

  int row = rbase + col;
  float sum = 0.f, sq = 0.f;
#pragma unroll
  for (int ct = 0; ct < 4; ++ct) {
    f32x4 bv = *(const f32x4*)(bf_ + w * 64 + ct * 16 + g * 4);
    f32x4 rs = *(const f32x4*)(resid + (size_t)row * DM + w * 64 + ct * 16 + g * 4);
#pragma unroll
    for (int r = 0; r < 4; ++r) {
      float xv = acc[ct][r] + bv[r] + rs[r];
      acc[ct][r] = xv;
      sum += xv;
      sq += xv * xv;
    }
  }
  sum += __shfl_xor(sum, 16); sum += __shfl_xor(sum, 32);
  sq += __shfl_xor(sq, 16);  sq += __shfl_xor(sq, 32);
  if (lane < 16) {  // g==0 lane per row
    lsum[col][w] = sum;
    lsq[col][w] = sq;
  }
  __syncthreads();
  float s_ = lsum[col][0] + lsum[col][1] + lsum[col][2] + lsum[col][3];
  float q_ = lsq[col][0] + lsq[col][1] + lsq[col][2] + lsq[col][3];
  float mu = s_ * (1.0f / 256.0f);
  float var = q_ * (1.0f / 256.0f) - mu * mu;
  float rstd = rsqrtf(var + LN_EPS);
#pragma unroll
  for (int ct = 0; ct < 4; ++ct) {
    f32x4 gm = *(const f32x4*)(gamma + w * 64 + ct * 16 + g * 4);
    f32x4 bt = *(const f32x4*)(beta + w * 64 + ct * 16 + g * 4);
    f32x4 o;
#pragma unroll
    for (int r = 0; r < 4; ++r)
      o[r] = gm[r] * (acc[ct][r] - mu) * rstd + bt[r];
    *(f32x4*)(out + (size_t)row * DM + w * 64 + ct * 16 + g * 4) = o;
  }
}

// ---------------------------------------------------------------------------
extern "C" void kernel_launch(void* const* d_in, const int* in_sizes, int n_in,
                              void* d_out, int out_size, void* d_ws,
                              size_t ws_size, hipStream_t stream) {
  const float* q     = (const float*)d_in[0];
  const float* k     = (const float*)d_in[1];
  const float* v     = (const float*)d_in[2];
  const int*   mask  = (const int*)d_in[3];
  const float* wq    = (const float*)d_in[4];
  const float* bq    = (const float*)d_in[5];
  const float* wk    = (const float*)d_in[6];
  const float* bk    = (const float*)d_in[7];
  const float* wv    = (const float*)d_in[8];
  const float* bv    = (const float*)d_in[9];
  const float* wf    = (const float*)d_in[10];
  const float* bf_   = (const float*)d_in[11];
  const float* gamma = (const float*)d_in[12];
  const float* beta  = (const float*)d_in[13];

  char* ws = (char*)d_ws;
  bf16* wqT = (bf16*)(ws);
  bf16* wkT = (bf16*)(ws + (1 << 17));
  bf16* wvT = (bf16*)(ws + 2 * (1 << 17));
  bf16* wfT = (bf16*)(ws + 3 * (1 << 17));
  float* maskadd = (float*)(ws + 4 * (1 << 17));
  bf16* qh = (bf16*)(ws + 4 * (1 << 17) + (1 << 16));
  bf16* kh = qh + (size_t)16384 * 256;
  bf16* vhT = kh + (size_t)16384 * 256;
  float* aout = (float*)(vhT + (size_t)16384 * 256);

  float* out_f = (float*)d_out;
  float* attn_f = out_f + (size_t)16384 * 256;

  prep_kernel<<<1088, 256, 0, stream>>>(wq, wk, wv, wf, mask, wqT, wkT, wvT,
                                        wfT, maskadd);
  proj_kernel<0><<<dim3(256, 4), 256, 0, stream>>>(q, wqT, bq, 0.125f, qh);
  proj_kernel<0><<<dim3(256, 4), 256, 0, stream>>>(k, wkT, bk, 1.0f, kh);
  proj_kernel<1><<<dim3(256, 4), 256, 0, stream>>>(v, wvT, bv, 1.0f, vhT);
  attn_kernel<<<1024, 256, 0, stream>>>(qh, kh, vhT, maskadd, attn_f, aout);
  final_kernel<<<1024, 256, 0, stream>>>(aout, wfT, bf_, q, gamma, beta, out_f);
}